// Round 18
// baseline (148.859 us; speedup 1.0000x reference)
//
#include <hip/hip_runtime.h>
#include <math.h>

#define N_FEAT_IN 256
#define N_HID 64
#define N_OUT 16
#define EPS 0.1f

typedef short bf16x8 __attribute__((ext_vector_type(8)));
typedef float f32x4 __attribute__((ext_vector_type(4)));

__device__ inline uint pack2(ushort a, ushort b) { return (uint)a | ((uint)b << 16); }

// fp32 -> bf16 round-to-nearest-even (inputs finite; no NaN handling needed)
__device__ inline ushort bf16_rne(float x) {
    uint b = __float_as_uint(x);
    b += 0x7fff + ((b >> 16) & 1);
    return (ushort)(b >> 16);
}

// unpack the two bf16 halves of a uint
__device__ inline float blo(uint u) { return __uint_as_float(u << 16); }
__device__ inline float bhi(uint u) { return __uint_as_float(u & 0xffff0000u); }

// truncation-based fp32 -> bf16 hi/lo split: x ~= hi + lo, |err| <= 2^-18 |x|
__device__ inline void split_bf16(float x, ushort& hi, ushort& lo) {
    uint b = __float_as_uint(x);
    hi = (ushort)(b >> 16);
    float xl = x - __uint_as_float(b & 0xffff0000u);
    lo = (ushort)(__float_as_uint(xl) >> 16);
}

// ---------------- zero (runtime fillBuffer is ~40us inside a graph) ----------------

__global__ void zero_int(int* __restrict__ p, int n) {
    int i = blockIdx.x * blockDim.x + threadIdx.x;
    if (i < n) p[i] = 0;
}

// ---------------- degree histogram, fused rank+row pack ----------------

__global__ void hist_rank(const int* __restrict__ col, const int* __restrict__ row,
                          int* __restrict__ cnt, uint* __restrict__ rr, int E) {
    int e = blockIdx.x * blockDim.x + threadIdx.x;
    if (e < E) {
        int r = atomicAdd(&cnt[col[e]], 1);
        rr[e] = ((uint)r << 16) | (uint)row[e];
    }
}

// ---------------- 2-level exclusive scan (N <= 256*256), dinv fused ----------------

__global__ void scan_chunks(const int* __restrict__ cnt, int* __restrict__ rowptr,
                            int* __restrict__ partial, float* __restrict__ dinv, int N) {
    __shared__ int sm[256];
    int tid = threadIdx.x;
    int gid = blockIdx.x * 256 + tid;
    int v = (gid < N) ? cnt[gid] : 0;
    sm[tid] = v;
    __syncthreads();
#pragma unroll
    for (int off = 1; off < 256; off <<= 1) {
        int add = (tid >= off) ? sm[tid - off] : 0;
        __syncthreads();
        sm[tid] += add;
        __syncthreads();
    }
    if (gid < N) {
        rowptr[gid] = sm[tid] - v;               // exclusive within chunk
        dinv[gid] = rsqrtf(1.0f + (float)v);     // +1 for self loop
    }
    if (tid == 255) partial[blockIdx.x] = sm[255];
}

__global__ void scan_finish(int* __restrict__ rowptr, const int* __restrict__ partial,
                            int N, int E, int nchunks) {
    __shared__ int sm[256];
    int tid = threadIdx.x;
    sm[tid] = (tid < nchunks) ? partial[tid] : 0;
    __syncthreads();
#pragma unroll
    for (int off = 1; off < 256; off <<= 1) {
        int add = (tid >= off) ? sm[tid - off] : 0;
        __syncthreads();
        sm[tid] += add;
        __syncthreads();
    }
    int boff = (blockIdx.x == 0) ? 0 : sm[blockIdx.x - 1];
    __syncthreads();
    int gid = blockIdx.x * 256 + tid;
    if (gid < N) rowptr[gid] += boff;
    if (gid == 0) rowptr[N] = E;
}

// ---------------- atomic-free XCD-range-partitioned CSR scatter ----------------

__global__ void csr_scatter_part(const int* __restrict__ col, const uint* __restrict__ rr,
                                 const int* __restrict__ rowptr,
                                 ushort* __restrict__ srcidx, int E, int rangeSz) {
    int r = blockIdx.x & 7;
    int nsl = gridDim.x >> 3;
    int s = blockIdx.x >> 3;
    int lo = r * rangeSz;
    int hi = lo + rangeSz;
    int stride = nsl * blockDim.x;
    for (int e = s * blockDim.x + threadIdx.x; e < E; e += stride) {
        int c = col[e];
        if (c >= lo && c < hi) {
            uint v = rr[e];
            srcidx[rowptr[c] + (v >> 16)] = (ushort)(v & 0xffffu);
        }
    }
}

// ---------------- As1 = dinv * relu(x @ W1 + b1), bf16x3 MFMA, LDS-streamed x --------
// Output split column-wise into Lo (feats 0-31) / Hi (32-63) arrays so each
// layer half-pass gathers from a 3.2 MB array that fits one XCD's 4 MB L2.

__global__ __launch_bounds__(256) void gemm1_mfma(const float* __restrict__ x,
                                                  const float* __restrict__ W1,
                                                  const float* __restrict__ b1,
                                                  const float* __restrict__ dinv,
                                                  uint* __restrict__ LoOut,
                                                  uint* __restrict__ HiOut,
                                                  int MB) {
    __shared__ uint4 wh_lds[2048];   // 32 KB: [ks][nt][lane] hi fragments
    __shared__ uint4 wl_lds[2048];   // 32 KB: lo fragments
    __shared__ float4 xt4[1024];     // 16 KB: x tile, [r][c4 ^ (r&7)]
    int tid = threadIdx.x;
    for (int e = tid; e < 2048; e += 256) {
        int ks = e >> 8;
        int rem = e & 255;
        int nt = rem >> 6;
        int ln = rem & 63;
        int k0 = ks * 32 + ((ln >> 4) << 3);
        int colw = nt * 16 + (ln & 15);
        ushort hi[8], lo[8];
#pragma unroll
        for (int i = 0; i < 8; ++i) {
            float v = W1[(k0 + i) * 64 + colw];
            split_bf16(v, hi[i], lo[i]);
        }
        wh_lds[e] = make_uint4(pack2(hi[0], hi[1]), pack2(hi[2], hi[3]),
                               pack2(hi[4], hi[5]), pack2(hi[6], hi[7]));
        wl_lds[e] = make_uint4(pack2(lo[0], lo[1]), pack2(lo[2], lo[3]),
                               pack2(lo[4], lo[5]), pack2(lo[6], lo[7]));
    }
    // first loop iteration's __syncthreads() covers W staging

    int lane = tid & 63;
    int m = lane & 15;       // A row within tile / D col within nt-tile
    int g = lane >> 4;       // k-group
    int w = tid >> 6;        // wave id = output col-tile nt
    const bf16x8* whf = reinterpret_cast<const bf16x8*>(wh_lds);
    const bf16x8* wlf = reinterpret_cast<const bf16x8*>(wl_lds);
    float bias = b1[w * 16 + m];
    int swz = m & 7;
    uint* dstH = (w < 2) ? LoOut : HiOut;
    int ci = ((w & 1) * 16 + m) >> 1;   // uint index within half row [0,16)

    for (int mb = blockIdx.x; mb < MB; mb += gridDim.x) {
        __syncthreads();     // xt4 free (prev tile's readers done; 1st iter: W staged)
        const float4* xg = reinterpret_cast<const float4*>(x) + (size_t)mb * 1024;
#pragma unroll
        for (int t = 0; t < 4; ++t) {
            int F = t * 256 + tid;          // float4 index within tile
            int r = F >> 6, c4 = F & 63;
            xt4[r * 64 + (c4 ^ (r & 7))] = xg[F];   // coalesced read, swizzled store
        }
        __syncthreads();

        f32x4 acc = {0.f, 0.f, 0.f, 0.f};
#pragma unroll
        for (int ks = 0; ks < 8; ++ks) {
            int c4 = ks * 8 + g * 2;
            float4 a0 = xt4[m * 64 + ((c4) ^ swz)];
            float4 a1 = xt4[m * 64 + ((c4 + 1) ^ swz)];
            float f[8] = {a0.x, a0.y, a0.z, a0.w, a1.x, a1.y, a1.z, a1.w};
            bf16x8 ah, al;
#pragma unroll
            for (int i = 0; i < 8; ++i) {
                ushort hu, lu;
                split_bf16(f[i], hu, lu);
                ah[i] = (short)hu;
                al[i] = (short)lu;
            }
            bf16x8 wh = whf[(ks * 4 + w) * 64 + lane];
            bf16x8 wl = wlf[(ks * 4 + w) * 64 + lane];
            acc = __builtin_amdgcn_mfma_f32_16x16x32_bf16(ah, wh, acc, 0, 0, 0);
            acc = __builtin_amdgcn_mfma_f32_16x16x32_bf16(al, wh, acc, 0, 0, 0);
            acc = __builtin_amdgcn_mfma_f32_16x16x32_bf16(ah, wl, acc, 0, 0, 0);
        }

        int r0 = mb * 16 + g * 4;
#pragma unroll
        for (int j = 0; j < 4; ++j) {
            float v = fmaxf(acc[j] + bias, 0.0f) * dinv[r0 + j];
            float p = __shfl_xor(v, 1, 64);  // partner column (m^1)
            if ((m & 1) == 0) {
                uint u = pack2(bf16_rne(v), bf16_rne(p));
                dstH[(size_t)(r0 + j) * 16 + ci] = u;
            }
        }
    }
}

// ---------------- FAGCN half-pass: gather ONE 3.2MB feature half (L2-resident) -------
// 4 lanes/node, each lane one uint4 (8 bf16 feats = 16 B) of the half. Gate is
// computed independently in each pass from the (streamed) full self row — the
// two half-passes of a layer are fully independent, no temp arrays.
// LAST writes h (bf16, unscaled) for the separate gemm2; else writes d*h.

template <int HALF, bool LAST>
__global__ __launch_bounds__(256) void fagcn_half(
    const uint4* __restrict__ LoIn, const uint4* __restrict__ HiIn,
    uint4* __restrict__ OutH,
    const float* __restrict__ dinv, const int* __restrict__ rowptr,
    const ushort* __restrict__ src, const float* __restrict__ att_l, int N) {
    int tid = threadIdx.x;
    int sub = tid & 3;               // uint4 index within half row
    int lnode = tid >> 2;            // node within block (0..63)
    int i = blockIdx.x * 64 + lnode;
    if (i >= N) i = N - 1;           // duplicate last node (identical writes, benign)

    int start = rowptr[i];
    int end = rowptr[i + 1];
    const uint4* G = ((HALF == 0) ? LoIn : HiIn) + sub;   // gather array (hot, 3.2 MB)

    // self rows, both halves (streamed once; gate needs the full row)
    uint4 sl = LoIn[(size_t)i * 4 + sub];
    uint4 sh = HiIn[(size_t)i * 4 + sub];

    float aA0=0.f,aA1=0.f,aA2=0.f,aA3=0.f,aA4=0.f,aA5=0.f,aA6=0.f,aA7=0.f;
    float aB0=0.f,aB1=0.f,aB2=0.f,aB3=0.f,aB4=0.f,aB5=0.f,aB6=0.f,aB7=0.f;
    int j = start;
    for (; j + 3 < end; j += 4) {
        int e0 = src[j];
        int e1 = src[j + 1];
        int e2 = src[j + 2];
        int e3 = src[j + 3];
        uint4 u0 = G[(size_t)e0 * 4];
        uint4 u1 = G[(size_t)e1 * 4];
        uint4 u2 = G[(size_t)e2 * 4];
        uint4 u3 = G[(size_t)e3 * 4];
        aA0 += blo(u0.x); aA1 += bhi(u0.x); aA2 += blo(u0.y); aA3 += bhi(u0.y);
        aA4 += blo(u0.z); aA5 += bhi(u0.z); aA6 += blo(u0.w); aA7 += bhi(u0.w);
        aB0 += blo(u1.x); aB1 += bhi(u1.x); aB2 += blo(u1.y); aB3 += bhi(u1.y);
        aB4 += blo(u1.z); aB5 += bhi(u1.z); aB6 += blo(u1.w); aB7 += bhi(u1.w);
        aA0 += blo(u2.x); aA1 += bhi(u2.x); aA2 += blo(u2.y); aA3 += bhi(u2.y);
        aA4 += blo(u2.z); aA5 += bhi(u2.z); aA6 += blo(u2.w); aA7 += bhi(u2.w);
        aB0 += blo(u3.x); aB1 += bhi(u3.x); aB2 += blo(u3.y); aB3 += bhi(u3.y);
        aB4 += blo(u3.z); aB5 += bhi(u3.z); aB6 += blo(u3.w); aB7 += bhi(u3.w);
    }
    for (; j < end; ++j) {
        int s = src[j];
        uint4 u = G[(size_t)s * 4];
        aA0 += blo(u.x); aA1 += bhi(u.x); aA2 += blo(u.y); aA3 += bhi(u.y);
        aA4 += blo(u.z); aA5 += bhi(u.z); aA6 += blo(u.w); aA7 += bhi(u.w);
    }
    float c0 = aA0 + aB0, c1 = aA1 + aB1, c2 = aA2 + aB2, c3 = aA3 + aB3;
    float c4 = aA4 + aB4, c5 = aA5 + aB5, c6 = aA6 + aB6, c7 = aA7 + aB7;

    float d = dinv[i];
    // full gate dot: this lane covers feats sub*8..+8 (lo) and 32+sub*8..+8 (hi)
    const float4* at4 = reinterpret_cast<const float4*>(att_l);
    float4 al0 = at4[2 * sub],     al1 = at4[2 * sub + 1];
    float4 ah0 = at4[8 + 2 * sub], ah1 = at4[8 + 2 * sub + 1];
    float prod =
        blo(sl.x) * al0.x + bhi(sl.x) * al0.y + blo(sl.y) * al0.z + bhi(sl.y) * al0.w +
        blo(sl.z) * al1.x + bhi(sl.z) * al1.y + blo(sl.w) * al1.z + bhi(sl.w) * al1.w +
        blo(sh.x) * ah0.x + bhi(sh.x) * ah0.y + blo(sh.y) * ah0.z + bhi(sh.y) * ah0.w +
        blo(sh.z) * ah1.x + bhi(sh.z) * ah1.y + blo(sh.w) * ah1.z + bhi(sh.w) * ah1.w;
#pragma unroll
    for (int off = 1; off < 4; off <<= 1)
        prod += __shfl_xor(prod, off, 64);   // fold within 4-lane group
    float gate = 1.0f / (1.0f + expf(-prod / d));
    float factor = gate * (1.0f + EPS) - EPS;
    float df = d * factor;

    uint4 sm = (HALF == 0) ? sl : sh;        // self of OUR half
    float s0 = blo(sm.x), s1 = bhi(sm.x), s2 = blo(sm.y), s3 = bhi(sm.y);
    float s4 = blo(sm.z), s5 = bhi(sm.z), s6 = blo(sm.w), s7 = bhi(sm.w);
    float h0 = df * (c0 + s0), h1 = df * (c1 + s1);
    float h2 = df * (c2 + s2), h3 = df * (c3 + s3);
    float h4 = df * (c4 + s4), h5 = df * (c5 + s5);
    float h6 = df * (c6 + s6), h7 = df * (c7 + s7);

    float sc = LAST ? 1.0f : d;              // next layer input is pre-scaled by d
    OutH[(size_t)i * 4 + sub] =
        make_uint4(pack2(bf16_rne(sc * h0), bf16_rne(sc * h1)),
                   pack2(bf16_rne(sc * h2), bf16_rne(sc * h3)),
                   pack2(bf16_rne(sc * h4), bf16_rne(sc * h5)),
                   pack2(bf16_rne(sc * h6), bf16_rne(sc * h7)));
}

// ---------------- out = h @ W2 + b2 (bf16 h in Lo/Hi halves), 16 lanes/row ----------

__global__ void gemm2_bf16(const uint4* __restrict__ hLo, const uint4* __restrict__ hHi,
                           const float* __restrict__ W2, const float* __restrict__ b2,
                           float* __restrict__ out, int N) {
    int t = blockIdx.x * blockDim.x + threadIdx.x;
    int r = t >> 4;
    int c = t & 15;
    if (r >= N) return;
    float acc = b2[c];
#pragma unroll
    for (int q = 0; q < 4; ++q) {
        uint4 u = hLo[(size_t)r * 4 + q];
        int k = q * 8;
        acc = fmaf(blo(u.x), W2[(k + 0) * 16 + c], acc);
        acc = fmaf(bhi(u.x), W2[(k + 1) * 16 + c], acc);
        acc = fmaf(blo(u.y), W2[(k + 2) * 16 + c], acc);
        acc = fmaf(bhi(u.y), W2[(k + 3) * 16 + c], acc);
        acc = fmaf(blo(u.z), W2[(k + 4) * 16 + c], acc);
        acc = fmaf(bhi(u.z), W2[(k + 5) * 16 + c], acc);
        acc = fmaf(blo(u.w), W2[(k + 6) * 16 + c], acc);
        acc = fmaf(bhi(u.w), W2[(k + 7) * 16 + c], acc);
    }
#pragma unroll
    for (int q = 0; q < 4; ++q) {
        uint4 u = hHi[(size_t)r * 4 + q];
        int k = 32 + q * 8;
        acc = fmaf(blo(u.x), W2[(k + 0) * 16 + c], acc);
        acc = fmaf(bhi(u.x), W2[(k + 1) * 16 + c], acc);
        acc = fmaf(blo(u.y), W2[(k + 2) * 16 + c], acc);
        acc = fmaf(bhi(u.y), W2[(k + 3) * 16 + c], acc);
        acc = fmaf(blo(u.z), W2[(k + 4) * 16 + c], acc);
        acc = fmaf(bhi(u.z), W2[(k + 5) * 16 + c], acc);
        acc = fmaf(blo(u.w), W2[(k + 6) * 16 + c], acc);
        acc = fmaf(bhi(u.w), W2[(k + 7) * 16 + c], acc);
    }
    out[(size_t)r * 16 + c] = acc;
}

extern "C" void kernel_launch(void* const* d_in, const int* in_sizes, int n_in,
                              void* d_out, int out_size, void* d_ws, size_t ws_size,
                              hipStream_t stream) {
    const float* x   = (const float*)d_in[0];   // [N, 256]
    const int*   ei  = (const int*)d_in[1];     // [2, E] flat (int32 per harness)
    const float* W1  = (const float*)d_in[2];   // [256, 64]
    const float* b1  = (const float*)d_in[3];   // [64]
    const float* att = (const float*)d_in[4];   // [L, 1, 64]
    const float* W2  = (const float*)d_in[5];   // [64, 16]
    const float* b2  = (const float*)d_in[6];   // [16]
    float* out = (float*)d_out;                 // [N, 16]

    const int N = in_sizes[0] / N_FEAT_IN;      // 50000 (< 65536: ushort ids/ranks)
    const int E = in_sizes[1] / 2;              // 800000
    // L = 2 layers (att shape [2,1,64]); loop below uses it implicitly

    const int* row = ei;       // edge_index[0] (source)
    const int* col = ei + E;   // edge_index[1] (target)

    // workspace layout (256B-aligned regions)
    char* wp = (char*)d_ws;
    auto alloc = [&](size_t bytes) -> char* {
        char* p = wp;
        wp += (bytes + 255) & ~(size_t)255;
        return p;
    };
    float*  dinv    = (float*)alloc((size_t)N * 4);
    int*    cnt     = (int*)alloc((size_t)N * 4);
    int*    rowptr  = (int*)alloc((size_t)(N + 1) * 4);
    uint*   rr      = (uint*)alloc((size_t)E * 4);        // (rank<<16)|row per edge
    int*    partial = (int*)alloc(256 * 4);
    ushort* srcidx  = (ushort*)alloc((size_t)E * 2);
    uint*   LoA     = (uint*)alloc((size_t)N * 16 * 4);   // feats 0-31, 3.2 MB
    uint*   HiA     = (uint*)alloc((size_t)N * 16 * 4);   // feats 32-63
    uint*   LoB     = (uint*)alloc((size_t)N * 16 * 4);
    uint*   HiB     = (uint*)alloc((size_t)N * 16 * 4);

    const int TB = 256;
    const int nchunks = (N + TB - 1) / TB;      // 196 <= 256
    const int rangeSz = (N + 7) / 8;            // XCD partition width
    const int PART_GRID = 1024;                 // 128 slices x 8 ranges

    // 1) degree+rank in ONE atomic pass -> dinv, rowptr; atomic-free CSR scatter
    zero_int<<<(N + TB - 1) / TB, TB, 0, stream>>>(cnt, N);
    hist_rank<<<(E + TB - 1) / TB, TB, 0, stream>>>(col, row, cnt, rr, E);
    scan_chunks<<<nchunks, TB, 0, stream>>>(cnt, rowptr, partial, dinv, N);
    scan_finish<<<nchunks, TB, 0, stream>>>(rowptr, partial, N, E, nchunks);
    csr_scatter_part<<<PART_GRID, TB, 0, stream>>>(col, rr, rowptr, srcidx, E, rangeSz);

    // 2) As1 = dinv * relu(x @ W1 + b1) -> (LoA, HiA) bf16 halves
    {
        const int blocks = 512;                 // 80 KB LDS -> 2 blocks/CU
        const int MB = N / 16;                  // 3125 row-tiles
        gemm1_mfma<<<blocks, TB, 0, stream>>>(x, W1, b1, dinv, LoA, HiA, MB);
    }

    // 3) FAGCN layers as independent L2-resident half-passes
    {
        int grid = (N + 63) / 64;               // 64 nodes per 256-thread block
        const uint4* lA = (const uint4*)LoA; const uint4* hA = (const uint4*)HiA;
        uint4* lB = (uint4*)LoB; uint4* hB = (uint4*)HiB;
        // layer 0: (LoA,HiA) -> (LoB,HiB), pre-scaled
        fagcn_half<0, false><<<grid, TB, 0, stream>>>(lA, hA, lB, dinv, rowptr, srcidx, att, N);
        fagcn_half<1, false><<<grid, TB, 0, stream>>>(lA, hA, hB, dinv, rowptr, srcidx, att, N);
        // layer 1 (last): (LoB,HiB) -> h in (LoA,HiA), unscaled
        fagcn_half<0, true><<<grid, TB, 0, stream>>>(lB, hB, (uint4*)LoA, dinv, rowptr, srcidx, att + 64, N);
        fagcn_half<1, true><<<grid, TB, 0, stream>>>(lB, hB, (uint4*)HiA, dinv, rowptr, srcidx, att + 64, N);
    }

    // 4) out = h @ W2 + b2
    {
        long long threads = (long long)N * N_OUT;
        gemm2_bf16<<<(int)((threads + TB - 1) / TB), TB, 0, stream>>>(
            (const uint4*)LoA, (const uint4*)HiA, W2, b2, out, N);
    }
}

// Round 19
// 123.373 us; speedup vs baseline: 1.2066x; 1.2066x over previous
//
#include <hip/hip_runtime.h>
#include <math.h>

#define N_FEAT_IN 256
#define N_HID 64
#define N_OUT 16
#define EPS 0.1f

typedef short bf16x8 __attribute__((ext_vector_type(8)));
typedef float f32x4 __attribute__((ext_vector_type(4)));

__device__ inline uint pack2(ushort a, ushort b) { return (uint)a | ((uint)b << 16); }

// fp32 -> bf16 round-to-nearest-even (inputs finite; no NaN handling needed)
__device__ inline ushort bf16_rne(float x) {
    uint b = __float_as_uint(x);
    b += 0x7fff + ((b >> 16) & 1);
    return (ushort)(b >> 16);
}

// unpack the two bf16 halves of a uint
__device__ inline float blo(uint u) { return __uint_as_float(u << 16); }
__device__ inline float bhi(uint u) { return __uint_as_float(u & 0xffff0000u); }

// truncation-based fp32 -> bf16 hi/lo split: x ~= hi + lo, |err| <= 2^-18 |x|
__device__ inline void split_bf16(float x, ushort& hi, ushort& lo) {
    uint b = __float_as_uint(x);
    hi = (ushort)(b >> 16);
    float xl = x - __uint_as_float(b & 0xffff0000u);
    lo = (ushort)(__float_as_uint(xl) >> 16);
}

// ---------------- zero (runtime fillBuffer is ~40us inside a graph) ----------------

__global__ void zero_int(int* __restrict__ p, int n) {
    int i = blockIdx.x * blockDim.x + threadIdx.x;
    if (i < n) p[i] = 0;
}

// ---------------- degree histogram, fused rank+row pack ----------------
// One atomic pass total: the atomic's return value IS the edge's rank among its
// target's edges. rr[e] = (rank<<16) | row[e] (both < 65536).

__global__ void hist_rank(const int* __restrict__ col, const int* __restrict__ row,
                          int* __restrict__ cnt, uint* __restrict__ rr, int E) {
    int e = blockIdx.x * blockDim.x + threadIdx.x;
    if (e < E) {
        int r = atomicAdd(&cnt[col[e]], 1);
        rr[e] = ((uint)r << 16) | (uint)row[e];
    }
}

// ---------------- 2-level exclusive scan (N <= 256*256), dinv fused ----------------

__global__ void scan_chunks(const int* __restrict__ cnt, int* __restrict__ rowptr,
                            int* __restrict__ partial, float* __restrict__ dinv, int N) {
    __shared__ int sm[256];
    int tid = threadIdx.x;
    int gid = blockIdx.x * 256 + tid;
    int v = (gid < N) ? cnt[gid] : 0;
    sm[tid] = v;
    __syncthreads();
#pragma unroll
    for (int off = 1; off < 256; off <<= 1) {
        int add = (tid >= off) ? sm[tid - off] : 0;
        __syncthreads();
        sm[tid] += add;
        __syncthreads();
    }
    if (gid < N) {
        rowptr[gid] = sm[tid] - v;               // exclusive within chunk
        dinv[gid] = rsqrtf(1.0f + (float)v);     // +1 for self loop
    }
    if (tid == 255) partial[blockIdx.x] = sm[255];
}

// finish: every block redundantly scans the <=256 chunk partials in LDS (cheap)

__global__ void scan_finish(int* __restrict__ rowptr, const int* __restrict__ partial,
                            int N, int E, int nchunks) {
    __shared__ int sm[256];
    int tid = threadIdx.x;
    sm[tid] = (tid < nchunks) ? partial[tid] : 0;
    __syncthreads();
#pragma unroll
    for (int off = 1; off < 256; off <<= 1) {
        int add = (tid >= off) ? sm[tid - off] : 0;
        __syncthreads();
        sm[tid] += add;
        __syncthreads();
    }
    int boff = (blockIdx.x == 0) ? 0 : sm[blockIdx.x - 1];
    __syncthreads();
    int gid = blockIdx.x * 256 + tid;
    if (gid < N) rowptr[gid] += boff;
    if (gid == 0) rowptr[N] = E;
}

// ---------------- atomic-free XCD-range-partitioned CSR scatter ----------------

__global__ void csr_scatter_part(const int* __restrict__ col, const uint* __restrict__ rr,
                                 const int* __restrict__ rowptr,
                                 ushort* __restrict__ srcidx, int E, int rangeSz) {
    int r = blockIdx.x & 7;
    int nsl = gridDim.x >> 3;
    int s = blockIdx.x >> 3;
    int lo = r * rangeSz;
    int hi = lo + rangeSz;
    int stride = nsl * blockDim.x;
    for (int e = s * blockDim.x + threadIdx.x; e < E; e += stride) {
        int c = col[e];
        if (c >= lo && c < hi) {
            uint v = rr[e];
            srcidx[rowptr[c] + (v >> 16)] = (ushort)(v & 0xffffu);
        }
    }
}

// ---------------- As1 = dinv * relu(x @ W1 + b1), bf16x3 MFMA, LDS-streamed x --------
// The MFMA A-fragment wants lane g*16+r to hold row r -> a register-direct x load
// is a 16B-granular scatter (measured 757 GB/s in R7). Fix: cooperatively stream
// each 16x256 x-tile into LDS with coalesced 16B/lane loads, then ds_read the
// fragments. float4-index XOR swizzle (c4 ^= r&7) keeps fragment reads bank-even
// with zero padding -> LDS = 64KB (W hi/lo) + 16KB (x) = 80KB -> 2 blocks/CU.
// Wave w owns output-column tile nt=w. K-perm-invariant mapping k=(lane>>4)*8+i
// used identically for A and B. C/D: col=lane&15, row=(lane>>4)*4+reg.

__global__ __launch_bounds__(256) void gemm1_mfma(const float* __restrict__ x,
                                                  const float* __restrict__ W1,
                                                  const float* __restrict__ b1,
                                                  const float* __restrict__ dinv,
                                                  uint* __restrict__ AsOut,
                                                  int MB) {
    __shared__ uint4 wh_lds[2048];   // 32 KB: [ks][nt][lane] hi fragments
    __shared__ uint4 wl_lds[2048];   // 32 KB: lo fragments
    __shared__ float4 xt4[1024];     // 16 KB: x tile, [r][c4 ^ (r&7)]
    int tid = threadIdx.x;
    for (int e = tid; e < 2048; e += 256) {
        int ks = e >> 8;
        int rem = e & 255;
        int nt = rem >> 6;
        int ln = rem & 63;
        int k0 = ks * 32 + ((ln >> 4) << 3);
        int colw = nt * 16 + (ln & 15);
        ushort hi[8], lo[8];
#pragma unroll
        for (int i = 0; i < 8; ++i) {
            float v = W1[(k0 + i) * 64 + colw];
            split_bf16(v, hi[i], lo[i]);
        }
        wh_lds[e] = make_uint4(pack2(hi[0], hi[1]), pack2(hi[2], hi[3]),
                               pack2(hi[4], hi[5]), pack2(hi[6], hi[7]));
        wl_lds[e] = make_uint4(pack2(lo[0], lo[1]), pack2(lo[2], lo[3]),
                               pack2(lo[4], lo[5]), pack2(lo[6], lo[7]));
    }
    // first loop iteration's __syncthreads() covers W staging

    int lane = tid & 63;
    int m = lane & 15;       // A row within tile / D col within nt-tile
    int g = lane >> 4;       // k-group
    int w = tid >> 6;        // wave id = output col-tile nt
    const bf16x8* whf = reinterpret_cast<const bf16x8*>(wh_lds);
    const bf16x8* wlf = reinterpret_cast<const bf16x8*>(wl_lds);
    float bias = b1[w * 16 + m];
    int swz = m & 7;

    for (int mb = blockIdx.x; mb < MB; mb += gridDim.x) {
        __syncthreads();     // xt4 free (prev tile's readers done; 1st iter: W staged)
        const float4* xg = reinterpret_cast<const float4*>(x) + (size_t)mb * 1024;
#pragma unroll
        for (int t = 0; t < 4; ++t) {
            int F = t * 256 + tid;          // float4 index within tile
            int r = F >> 6, c4 = F & 63;
            xt4[r * 64 + (c4 ^ (r & 7))] = xg[F];   // coalesced read, swizzled store
        }
        __syncthreads();

        f32x4 acc = {0.f, 0.f, 0.f, 0.f};
#pragma unroll
        for (int ks = 0; ks < 8; ++ks) {
            int c4 = ks * 8 + g * 2;
            float4 a0 = xt4[m * 64 + ((c4) ^ swz)];
            float4 a1 = xt4[m * 64 + ((c4 + 1) ^ swz)];
            float f[8] = {a0.x, a0.y, a0.z, a0.w, a1.x, a1.y, a1.z, a1.w};
            bf16x8 ah, al;
#pragma unroll
            for (int i = 0; i < 8; ++i) {
                ushort hu, lu;
                split_bf16(f[i], hu, lu);
                ah[i] = (short)hu;
                al[i] = (short)lu;
            }
            bf16x8 wh = whf[(ks * 4 + w) * 64 + lane];
            bf16x8 wl = wlf[(ks * 4 + w) * 64 + lane];
            acc = __builtin_amdgcn_mfma_f32_16x16x32_bf16(ah, wh, acc, 0, 0, 0);
            acc = __builtin_amdgcn_mfma_f32_16x16x32_bf16(al, wh, acc, 0, 0, 0);
            acc = __builtin_amdgcn_mfma_f32_16x16x32_bf16(ah, wl, acc, 0, 0, 0);
        }

        int r0 = mb * 16 + g * 4;
#pragma unroll
        for (int j = 0; j < 4; ++j) {
            float v = fmaxf(acc[j] + bias, 0.0f) * dinv[r0 + j];
            float p = __shfl_xor(v, 1, 64);  // partner column (m^1)
            if ((m & 1) == 0) {
                uint u = pack2(bf16_rne(v), bf16_rne(p));
                AsOut[(size_t)(r0 + j) * 32 + ((w * 16 + m) >> 1)] = u;
            }
        }
    }
}

// ---------------- fused FAGCN layer, 8 nodes per wave ----------------
// 8 lanes per node, each lane owns 8 features (uint4 of bf16 pairs, 16 B/lane).
// LAST variant fuses out = h @ W2 + b2 via LDS (2 output cols per lane).

template <bool LAST>
__global__ __launch_bounds__(256) void fagcn_layer(
    const uint4* __restrict__ As4, uint4* __restrict__ Out4,
    const float* __restrict__ dinv, const int* __restrict__ rowptr,
    const ushort* __restrict__ src, const float* __restrict__ att_l,
    const float* __restrict__ W2, const float* __restrict__ b2,
    float* __restrict__ out, int N) {
    __shared__ float W2s[64 * 16];   // 4 KB
    __shared__ float hL[32 * 68];    // 32 nodes x 64 (+4 pad)
    int tid = threadIdx.x;
    if (LAST) {
        for (int e = tid; e < 64 * 16; e += 256) W2s[e] = W2[e];
        __syncthreads();
    }
    int sub = tid & 7;               // feature octet index
    int lnode = tid >> 3;            // node within block (0..31)
    int i = blockIdx.x * 32 + lnode;
    if (i >= N) i = N - 1;           // duplicate last node (identical writes, benign)

    int start = rowptr[i];
    int end = rowptr[i + 1];
    const uint4* Ab = As4 + sub;
    uint4 su = Ab[(size_t)i * 8];
    float s0 = blo(su.x), s1 = bhi(su.x), s2 = blo(su.y), s3 = bhi(su.y);
    float s4 = blo(su.z), s5 = bhi(su.z), s6 = blo(su.w), s7 = bhi(su.w);

    float aA0=0.f,aA1=0.f,aA2=0.f,aA3=0.f,aA4=0.f,aA5=0.f,aA6=0.f,aA7=0.f;
    float aB0=0.f,aB1=0.f,aB2=0.f,aB3=0.f,aB4=0.f,aB5=0.f,aB6=0.f,aB7=0.f;
    int j = start;
    for (; j + 3 < end; j += 4) {
        int e0 = src[j];
        int e1 = src[j + 1];
        int e2 = src[j + 2];
        int e3 = src[j + 3];
        uint4 u0 = Ab[(size_t)e0 * 8];
        uint4 u1 = Ab[(size_t)e1 * 8];
        uint4 u2 = Ab[(size_t)e2 * 8];
        uint4 u3 = Ab[(size_t)e3 * 8];
        aA0 += blo(u0.x); aA1 += bhi(u0.x); aA2 += blo(u0.y); aA3 += bhi(u0.y);
        aA4 += blo(u0.z); aA5 += bhi(u0.z); aA6 += blo(u0.w); aA7 += bhi(u0.w);
        aB0 += blo(u1.x); aB1 += bhi(u1.x); aB2 += blo(u1.y); aB3 += bhi(u1.y);
        aB4 += blo(u1.z); aB5 += bhi(u1.z); aB6 += blo(u1.w); aB7 += bhi(u1.w);
        aA0 += blo(u2.x); aA1 += bhi(u2.x); aA2 += blo(u2.y); aA3 += bhi(u2.y);
        aA4 += blo(u2.z); aA5 += bhi(u2.z); aA6 += blo(u2.w); aA7 += bhi(u2.w);
        aB0 += blo(u3.x); aB1 += bhi(u3.x); aB2 += blo(u3.y); aB3 += bhi(u3.y);
        aB4 += blo(u3.z); aB5 += bhi(u3.z); aB6 += blo(u3.w); aB7 += bhi(u3.w);
    }
    for (; j < end; ++j) {
        int s = src[j];
        uint4 u = Ab[(size_t)s * 8];
        aA0 += blo(u.x); aA1 += bhi(u.x); aA2 += blo(u.y); aA3 += bhi(u.y);
        aA4 += blo(u.z); aA5 += bhi(u.z); aA6 += blo(u.w); aA7 += bhi(u.w);
    }
    float c0 = aA0 + aB0, c1 = aA1 + aB1, c2 = aA2 + aB2, c3 = aA3 + aB3;
    float c4 = aA4 + aB4, c5 = aA5 + aB5, c6 = aA6 + aB6, c7 = aA7 + aB7;

    float d = dinv[i];
    // gate = sigmoid(dot(h_row, att)) with h = As/d
    float4 at0 = reinterpret_cast<const float4*>(att_l)[2 * sub];
    float4 at1 = reinterpret_cast<const float4*>(att_l)[2 * sub + 1];
    float prod = s0 * at0.x + s1 * at0.y + s2 * at0.z + s3 * at0.w +
                 s4 * at1.x + s5 * at1.y + s6 * at1.z + s7 * at1.w;
#pragma unroll
    for (int off = 4; off > 0; off >>= 1)
        prod += __shfl_xor(prod, off, 64);   // fold within 8-lane group
    float gate = 1.0f / (1.0f + expf(-prod / d));
    float factor = gate * (1.0f + EPS) - EPS;
    float df = d * factor;
    float h0 = df * (c0 + s0), h1 = df * (c1 + s1);
    float h2 = df * (c2 + s2), h3 = df * (c3 + s3);
    float h4 = df * (c4 + s4), h5 = df * (c5 + s5);
    float h6 = df * (c6 + s6), h7 = df * (c7 + s7);

    if (!LAST) {
        Out4[(size_t)i * 8 + sub] =
            make_uint4(pack2(bf16_rne(d * h0), bf16_rne(d * h1)),
                       pack2(bf16_rne(d * h2), bf16_rne(d * h3)),
                       pack2(bf16_rne(d * h4), bf16_rne(d * h5)),
                       pack2(bf16_rne(d * h6), bf16_rne(d * h7)));
    } else {
        // fused gemm2: h -> LDS, then each lane computes 2 output columns
        float4* hrow4 = reinterpret_cast<float4*>(&hL[lnode * 68]);
        hrow4[2 * sub]     = make_float4(h0, h1, h2, h3);
        hrow4[2 * sub + 1] = make_float4(h4, h5, h6, h7);
        __syncthreads();
        const float4* h4p = reinterpret_cast<const float4*>(&hL[lnode * 68]);
        float accA = b2[sub];
        float accB = b2[sub + 8];
#pragma unroll
        for (int k4 = 0; k4 < 16; ++k4) {
            float4 hv = h4p[k4];
            int k = 4 * k4;
            accA = fmaf(hv.x, W2s[(k + 0) * 16 + sub], accA);
            accB = fmaf(hv.x, W2s[(k + 0) * 16 + sub + 8], accB);
            accA = fmaf(hv.y, W2s[(k + 1) * 16 + sub], accA);
            accB = fmaf(hv.y, W2s[(k + 1) * 16 + sub + 8], accB);
            accA = fmaf(hv.z, W2s[(k + 2) * 16 + sub], accA);
            accB = fmaf(hv.z, W2s[(k + 2) * 16 + sub + 8], accB);
            accA = fmaf(hv.w, W2s[(k + 3) * 16 + sub], accA);
            accB = fmaf(hv.w, W2s[(k + 3) * 16 + sub + 8], accB);
        }
        out[(size_t)i * 16 + sub] = accA;
        out[(size_t)i * 16 + sub + 8] = accB;
    }
}

extern "C" void kernel_launch(void* const* d_in, const int* in_sizes, int n_in,
                              void* d_out, int out_size, void* d_ws, size_t ws_size,
                              hipStream_t stream) {
    const float* x   = (const float*)d_in[0];   // [N, 256]
    const int*   ei  = (const int*)d_in[1];     // [2, E] flat (int32 per harness)
    const float* W1  = (const float*)d_in[2];   // [256, 64]
    const float* b1  = (const float*)d_in[3];   // [64]
    const float* att = (const float*)d_in[4];   // [L, 1, 64]
    const float* W2  = (const float*)d_in[5];   // [64, 16]
    const float* b2  = (const float*)d_in[6];   // [16]
    float* out = (float*)d_out;                 // [N, 16]

    const int N = in_sizes[0] / N_FEAT_IN;      // 50000 (< 65536: ushort ids/ranks)
    const int E = in_sizes[1] / 2;              // 800000
    const int L = in_sizes[4] / N_HID;          // 2 layers

    const int* row = ei;       // edge_index[0] (source)
    const int* col = ei + E;   // edge_index[1] (target)

    // workspace layout (256B-aligned regions)
    char* wp = (char*)d_ws;
    auto alloc = [&](size_t bytes) -> char* {
        char* p = wp;
        wp += (bytes + 255) & ~(size_t)255;
        return p;
    };
    float*  dinv    = (float*)alloc((size_t)N * 4);
    int*    cnt     = (int*)alloc((size_t)N * 4);
    int*    rowptr  = (int*)alloc((size_t)(N + 1) * 4);
    uint*   rr      = (uint*)alloc((size_t)E * 4);        // (rank<<16)|row per edge
    int*    partial = (int*)alloc(256 * 4);
    ushort* srcidx  = (ushort*)alloc((size_t)E * 2);
    uint*   AsA     = (uint*)alloc((size_t)N * 32 * 4);   // bf16-pair features
    uint*   AsB     = (uint*)alloc((size_t)N * 32 * 4);

    const int TB = 256;
    const int nchunks = (N + TB - 1) / TB;      // 196 <= 256
    const int rangeSz = (N + 7) / 8;            // XCD partition width
    const int PART_GRID = 1024;                 // 128 slices x 8 ranges

    // 1) degree+rank in ONE atomic pass -> dinv, rowptr; atomic-free CSR scatter
    zero_int<<<(N + TB - 1) / TB, TB, 0, stream>>>(cnt, N);
    hist_rank<<<(E + TB - 1) / TB, TB, 0, stream>>>(col, row, cnt, rr, E);
    scan_chunks<<<nchunks, TB, 0, stream>>>(cnt, rowptr, partial, dinv, N);
    scan_finish<<<nchunks, TB, 0, stream>>>(rowptr, partial, N, E, nchunks);
    csr_scatter_part<<<PART_GRID, TB, 0, stream>>>(col, rr, rowptr, srcidx, E, rangeSz);

    // 2) As1 = dinv * relu(x @ W1 + b1) -> AsA (bf16 pairs), LDS-streamed x
    {
        const int blocks = 512;                 // 80 KB LDS -> 2 blocks/CU
        const int MB = N / 16;                  // 3125 row-tiles
        gemm1_mfma<<<blocks, TB, 0, stream>>>(x, W1, b1, dinv, AsA, MB);
    }

    // 3) FAGCN layers; LAST fuses the final h @ W2 + b2
    {
        int grid = (N + 31) / 32;               // 32 nodes per 256-thread block
        uint4* A = (uint4*)AsA;
        uint4* B = (uint4*)AsB;
        for (int l = 0; l < L; ++l) {
            const float* att_l = att + (size_t)l * N_HID;
            if (l == L - 1) {
                fagcn_layer<true><<<grid, TB, 0, stream>>>(
                    A, B, dinv, rowptr, srcidx, att_l, W2, b2, out, N);
            } else {
                fagcn_layer<false><<<grid, TB, 0, stream>>>(
                    A, B, dinv, rowptr, srcidx, att_l, W2, b2, out, N);
                uint4* tmp = A; A = B; B = tmp;
            }
        }
    }
}